// Round 14
// baseline (2480.895 us; speedup 1.0000x reference)
//
#include <hip/hip_runtime.h>
#include <hip/hip_bf16.h>

typedef __bf16 bf16_t;
typedef __bf16 bf16x8 __attribute__((ext_vector_type(8)));
typedef __bf16 bf16x4 __attribute__((ext_vector_type(4)));
typedef float f32x4 __attribute__((ext_vector_type(4)));
typedef float f32x16 __attribute__((ext_vector_type(16)));
typedef unsigned short u16x8 __attribute__((ext_vector_type(8)));
typedef unsigned int u32x4 __attribute__((ext_vector_type(4)));

#define T_TOK 8192
#define E_DIM 2048
#define NHEAD 32
#define SEQLEN 1024
#define NSEQ 8
#define LDQ 6144

#if __has_builtin(__builtin_amdgcn_exp2f)
#define EXP2F(x) __builtin_amdgcn_exp2f(x)
#else
#define EXP2F(x) exp2f(x)
#endif

static __device__ inline unsigned cvtpk_bf16(float lo, float hi) {
    unsigned r;
    asm("v_cvt_pk_bf16_f32 %0, %1, %2" : "=v"(r) : "v"(lo), "v"(hi));
    return r;
}

static __device__ inline void plswap(unsigned &x, unsigned &y, bool lo_half) {
#if __has_builtin(__builtin_amdgcn_permlane32_swap)
    auto r = __builtin_amdgcn_permlane32_swap(x, y, false, false);
    x = r[0]; y = r[1];
#else
    unsigned xs = __shfl_xor(x, 32), ys = __shfl_xor(y, 32);
    unsigned nx = lo_half ? x : ys;
    unsigned ny = lo_half ? xs : y;
    x = nx; y = ny;
#endif
}

// ---------------- fused fp32 -> bf16 conversion (5 regions, 1 launch) ------
__global__ void cvt_all(const float* __restrict__ hid, const float* __restrict__ Wq,
                        const float* __restrict__ Wk, const float* __restrict__ Wv,
                        const float* __restrict__ Wo, bf16_t* __restrict__ hidB,
                        bf16_t* __restrict__ Wcat, bf16_t* __restrict__ WoB) {
    const int TE4 = (T_TOK * E_DIM) / 4;
    const int EE4 = (E_DIM * E_DIM) / 4;
    const float* src;
    bf16_t* dst;
    int n4, base, nb;
    const int bid = blockIdx.x;
    if (bid < 2048)      { src = hid; dst = hidB;              n4 = TE4; base = 0;    nb = 2048; }
    else if (bid < 2560) { src = Wq;  dst = Wcat;              n4 = EE4; base = 2048; nb = 512; }
    else if (bid < 3072) { src = Wk;  dst = Wcat + 4 * EE4;    n4 = EE4; base = 2560; nb = 512; }
    else if (bid < 3584) { src = Wv;  dst = Wcat + 8 * EE4;    n4 = EE4; base = 3072; nb = 512; }
    else                 { src = Wo;  dst = WoB;               n4 = EE4; base = 3584; nb = 512; }
    const int stride = nb * 256;
    for (int i = (bid - base) * 256 + threadIdx.x; i < n4; i += stride) {
        const float4 v = reinterpret_cast<const float4*>(src)[i];
        bf16x4 o;
        o[0] = (bf16_t)v.x; o[1] = (bf16_t)v.y; o[2] = (bf16_t)v.z; o[3] = (bf16_t)v.w;
        reinterpret_cast<bf16x4*>(dst)[i] = o;
    }
}

// ---------------- GEMM 256x256, BK=32, ring-2, 64KB LDS, 2 blocks/CU -------
// Same schedule family as R10 best (stage(t+1) at top, one vmcnt(0)+barrier
// per tile) but BK=32 so LDS = 2 x 32KB = 64KB -> TWO blocks co-resident
// per CU (16 waves). One block's barrier/vmcnt stall is covered by the other
// block's MFMA burst (m114 cross-block overlap — the m97-structure's TLP).
// __launch_bounds__(512,4) caps VGPR at 128 so 4 waves/SIMD fit.
template<bool OUT_BF16>
__global__ __launch_bounds__(512, 4)
void gemm32r(const bf16_t* __restrict__ A, const bf16_t* __restrict__ B,
             const float* __restrict__ b0, const float* __restrict__ b1,
             const float* __restrict__ b2, void* __restrict__ Cout,
             int M, int N, float qs, int qlim) {
    constexpr int K = 2048;
    constexpr int NK = K / 32;   // 64
    __shared__ alignas(16) unsigned char lds[65536];
    const int tid = threadIdx.x;
    const int wid = tid >> 6, l = tid & 63;
    const int cpx = gridDim.x >> 3;
    const int id = (blockIdx.x & 7) * cpx + (blockIdx.x >> 3);
    const int sb = id >> 5, si = id & 31;
    const int smw = (M >> 8) >> 3;
    const int bm = (sb % smw) * 8 + (si & 7);
    const int bn = (sb / smw) * 4 + (si >> 3);
    const int wrow = (wid >> 2) * 128, wcol = (wid & 3) * 64;
    const int lr = l & 15, lg = l >> 4;

    f32x4 acc[8][4] = {};

    const bf16_t* aBase = A + (size_t)(bm * 256) * K;
    const bf16_t* bBase = B + (size_t)(bn * 256) * K;
    const int sr = l >> 2;           // 0..15: row within 16-row chunk
    const int sc = (l & 3) * 16;     // byte col within 64B row

    auto stage = [&](int t, int buf) {
        unsigned char* base = lds + buf * 32768;
#pragma unroll
        for (int c = 0; c < 2; ++c) {
            const int chunk = wid * 2 + c;
            const int r = chunk * 16 + sr;
            const int cb = sc ^ (((r >> 1) & 3) << 4);
            __builtin_amdgcn_global_load_lds(
                (const __attribute__((address_space(1))) void*)(aBase + (size_t)r * K + t * 32 + (cb >> 1)),
                (__attribute__((address_space(3))) void*)(base + chunk * 1024), 16, 0, 0);
            __builtin_amdgcn_global_load_lds(
                (const __attribute__((address_space(1))) void*)(bBase + (size_t)r * K + t * 32 + (cb >> 1)),
                (__attribute__((address_space(3))) void*)(base + 16384 + chunk * 1024), 16, 0, 0);
        }
    };

    stage(0, 0);
    asm volatile("s_waitcnt vmcnt(0)" ::: "memory");
    __builtin_amdgcn_s_barrier();

#pragma unroll 1
    for (int t = 0; t < NK; ++t) {
        if (t + 1 < NK) stage(t + 1, (t + 1) & 1);   // buf read during t-1, free
        const unsigned char* Ab = lds + (t & 1) * 32768;
        const unsigned char* Bb = Ab + 16384;
        bf16x8 bfv[4], af[8];
#pragma unroll
        for (int n = 0; n < 4; ++n) {
            const int r = wcol + n * 16 + lr;
            bfv[n] = *reinterpret_cast<const bf16x8*>(Bb + r * 64 + ((lg * 16) ^ (((r >> 1) & 3) << 4)));
        }
#pragma unroll
        for (int m = 0; m < 8; ++m) {
            const int r = wrow + m * 16 + lr;
            af[m] = *reinterpret_cast<const bf16x8*>(Ab + r * 64 + ((lg * 16) ^ (((r >> 1) & 3) << 4)));
        }
        __builtin_amdgcn_s_setprio(1);
#pragma unroll
        for (int m = 0; m < 8; ++m)
#pragma unroll
            for (int n = 0; n < 4; ++n)
                acc[m][n] = __builtin_amdgcn_mfma_f32_16x16x32_bf16(af[m], bfv[n], acc[m][n], 0, 0, 0);
        __builtin_amdgcn_s_setprio(0);
        if (t == NK - 1) break;
        asm volatile("s_waitcnt vmcnt(0)" ::: "memory");  // stage(t+1) issued ~1 tile ago
        __builtin_amdgcn_s_barrier();
    }

    // epilogue: C[row=(l>>4)*4+j][col=l&15] per fragment
    const int r0 = bm * 256 + wrow + lg * 4;
    const int c0 = bn * 256 + wcol + lr;
#pragma unroll
    for (int n = 0; n < 4; ++n) {
        const int cc = c0 + n * 16;
        const float bias = (cc < 2048) ? b0[cc] : (cc < 4096 ? b1[cc - 2048] : b2[cc - 4096]);
        const float sc2 = (cc < qlim) ? qs : 1.0f;
#pragma unroll
        for (int m = 0; m < 8; ++m)
#pragma unroll
            for (int j = 0; j < 4; ++j) {
                const int rr = r0 + m * 16 + j;
                const float v = (acc[m][n][j] + bias) * sc2;
                if (OUT_BF16) ((bf16_t*)Cout)[(size_t)rr * N + cc] = (bf16_t)v;
                else          ((float*)Cout)[(size_t)rr * N + cc] = v;
            }
    }
}

// ---------------- GEMM 256x256, BK=64, ring-2 (R10 best — used for Wo) -----
template<bool OUT_BF16>
__global__ __launch_bounds__(512, 2)
void gemm64(const bf16_t* __restrict__ A, const bf16_t* __restrict__ B,
            const float* __restrict__ b0, const float* __restrict__ b1,
            const float* __restrict__ b2, void* __restrict__ Cout,
            int M, int N, float qs, int qlim) {
    constexpr int K = 2048;
    constexpr int NK = K / 64;   // 32
    __shared__ alignas(16) unsigned char lds[131072];
    const int tid = threadIdx.x;
    const int wid = tid >> 6, l = tid & 63;
    const int cpx = gridDim.x >> 3;
    const int id = (blockIdx.x & 7) * cpx + (blockIdx.x >> 3);
    const int sb = id >> 5, si = id & 31;
    const int smw = (M >> 8) >> 3;
    const int bm = (sb % smw) * 8 + (si & 7);
    const int bn = (sb / smw) * 4 + (si >> 3);
    const int wrow = (wid >> 2) * 128, wcol = (wid & 3) * 64;
    const int lr = l & 15, lg = l >> 4;

    f32x4 acc[8][4] = {};

    const bf16_t* aBase = A + (size_t)(bm * 256) * K;
    const bf16_t* bBase = B + (size_t)(bn * 256) * K;

    const int srw = l >> 3;
    const int scb0 = (l & 7) * 16;
    auto stage = [&](int t, int buf) {
        unsigned char* base = lds + buf * 65536;
#pragma unroll
        for (int i = 0; i < 4; ++i) {
            const int chunk = wid * 4 + i;
            const int r = chunk * 8 + srw;
            const int cb = scb0 ^ ((r & 7) << 4);
            __builtin_amdgcn_global_load_lds(
                (const __attribute__((address_space(1))) void*)(aBase + (size_t)r * K + t * 64 + (cb >> 1)),
                (__attribute__((address_space(3))) void*)(base + chunk * 1024), 16, 0, 0);
        }
#pragma unroll
        for (int i = 0; i < 4; ++i) {
            const int chunk = wid * 4 + i;
            const int r = chunk * 8 + srw;
            const int cb = scb0 ^ ((r & 7) << 4);
            __builtin_amdgcn_global_load_lds(
                (const __attribute__((address_space(1))) void*)(bBase + (size_t)r * K + t * 64 + (cb >> 1)),
                (__attribute__((address_space(3))) void*)(base + 32768 + chunk * 1024), 16, 0, 0);
        }
    };

    stage(0, 0);
    asm volatile("s_waitcnt vmcnt(0)" ::: "memory");
    __builtin_amdgcn_s_barrier();

#pragma unroll 1
    for (int t = 0; t < NK; ++t) {
        if (t + 1 < NK) stage(t + 1, (t + 1) & 1);
        const unsigned char* Ab = lds + (t & 1) * 65536;
        const unsigned char* Bb = Ab + 32768;
        bf16x8 af[8][2], bfv[4][2];
#pragma unroll
        for (int n = 0; n < 4; ++n) {
            const int r = wcol + n * 16 + lr;
#pragma unroll
            for (int ks = 0; ks < 2; ++ks)
                bfv[n][ks] = *reinterpret_cast<const bf16x8*>(
                    Bb + r * 128 + (((unsigned)(ks * 64 + lg * 16)) ^ ((r & 7) << 4)));
        }
#pragma unroll
        for (int m = 0; m < 8; ++m) {
            const int r = wrow + m * 16 + lr;
#pragma unroll
            for (int ks = 0; ks < 2; ++ks)
                af[m][ks] = *reinterpret_cast<const bf16x8*>(
                    Ab + r * 128 + (((unsigned)(ks * 64 + lg * 16)) ^ ((r & 7) << 4)));
        }
        __builtin_amdgcn_s_setprio(1);
#pragma unroll
        for (int m = 0; m < 8; ++m)
#pragma unroll
            for (int n = 0; n < 4; ++n)
#pragma unroll
                for (int ks = 0; ks < 2; ++ks)
                    acc[m][n] = __builtin_amdgcn_mfma_f32_16x16x32_bf16(af[m][ks], bfv[n][ks], acc[m][n], 0, 0, 0);
        __builtin_amdgcn_s_setprio(0);
        if (t == NK - 1) break;
        asm volatile("s_waitcnt vmcnt(0)" ::: "memory");
        __builtin_amdgcn_s_barrier();
    }

    const int r0 = bm * 256 + wrow + lg * 4;
    const int c0 = bn * 256 + wcol + lr;
#pragma unroll
    for (int n = 0; n < 4; ++n) {
        const int cc = c0 + n * 16;
        const float bias = (cc < 2048) ? b0[cc] : (cc < 4096 ? b1[cc - 2048] : b2[cc - 4096]);
        const float sc2 = (cc < qlim) ? qs : 1.0f;
#pragma unroll
        for (int m = 0; m < 8; ++m)
#pragma unroll
            for (int j = 0; j < 4; ++j) {
                const int rr = r0 + m * 16 + j;
                const float v = (acc[m][n][j] + bias) * sc2;
                if (OUT_BF16) ((bf16_t*)Cout)[(size_t)rr * N + cc] = (bf16_t)v;
                else          ((float*)Cout)[(size_t)rr * N + cc] = v;
            }
    }
}

// ---------------- Flash attention, 8-wave 32x32 swapped-QK^T, paired qt ----
__global__ __launch_bounds__(512, 2)
void attn_fwd3(const bf16_t* __restrict__ QKV, bf16_t* __restrict__ Og) {
    const int orig = blockIdx.x;               // 0..511
    const int id = (orig & 7) * 64 + (orig >> 3);
    const int grp = id >> 1;                   // (h, sq)
    const int pairIdx = id & 1;
    const int h = grp & 31;
    const int sq = grp >> 5;

    const int tid = threadIdx.x;
    const int w = tid >> 6;
    const int l = tid & 63;
    const int ll = l & 31;
    const int hi = l >> 5;
    const bool lo_half = (hi == 0);

    __shared__ alignas(16) unsigned char lds[65536];  // K[2][16KB] + V[2][16KB]

    const bf16_t* Qg = QKV;
    const bf16_t* Kg = QKV + 2048;
    const bf16_t* Vg = QKV + 4096;
    const size_t kvbase = (size_t)(sq * SEQLEN) * LDQ + h * 64;

    bf16x8 vr0, vr1;
    const int vk0 = l * 2;
    const int vd0 = w * 8;

    auto stageK = [&](int kt, int buf) {
#pragma unroll
        for (int c = 0; c < 2; ++c) {
            const int o = (w * 2 + c) * 1024 + l * 16;
            const int r = o >> 7;
            const int swb = (o & 127) ^ ((r & 7) << 4);
            const bf16_t* src = Kg + kvbase + (size_t)(kt * 128 + r) * LDQ + (swb >> 1);
            __builtin_amdgcn_global_load_lds(
                (const __attribute__((address_space(1))) void*)src,
                (__attribute__((address_space(3))) void*)(lds + buf * 16384 + (w * 2 + c) * 1024),
                16, 0, 0);
        }
    };
    auto loadV = [&](int kt) {
        const bf16_t* vp = Vg + kvbase + (size_t)(kt * 128 + vk0) * LDQ + vd0;
        vr0 = *reinterpret_cast<const bf16x8*>(vp);
        vr1 = *reinterpret_cast<const bf16x8*>(vp + LDQ);
    };
    auto writeV = [&](int buf) {
        u16x8 s0 = __builtin_bit_cast(u16x8, vr0);
        u16x8 s1 = __builtin_bit_cast(u16x8, vr1);
        unsigned char* vb = lds + 32768 + buf * 16384;
#pragma unroll
        for (int e = 0; e < 8; ++e) {
            const int d = vd0 + e;
            unsigned off = (unsigned)(d * 256 + vk0 * 2);
            off ^= ((unsigned)((d ^ (d >> 4)) & 15)) << 4;
            *reinterpret_cast<unsigned*>(vb + off) = (unsigned)s0[e] | ((unsigned)s1[e] << 16);
        }
    };

    const unsigned ksw = (unsigned)((l & 7) << 4);
    const unsigned kbase = (unsigned)(ll * 128 + hi * 16);

#pragma unroll 1
    for (int seg = 0; seg < 2; ++seg) {
        const int qt = pairIdx ? (seg ? 2 : 1) : (seg ? 3 : 0);

        const int q_glob = qt * 256 + w * 32 + ll;
        const bf16_t* qp = Qg + (size_t)(sq * SEQLEN + q_glob) * LDQ + h * 64 + hi * 8;
        bf16x8 qf[4];
#pragma unroll
        for (int dc = 0; dc < 4; ++dc)
            qf[dc] = *reinterpret_cast<const bf16x8*>(qp + dc * 16);

        const int nkt = 2 * qt + 2;
        const int q_wave_max = qt * 256 + w * 32 + 31;

        f32x16 oac[2] = {};
        float mrun = -3.0e38f, lsum = 0.f;

        stageK(0, 0);
        loadV(0);
        writeV(0);
        __syncthreads();

        int cur = 0;
        for (int kt = 0; kt < nkt; ++kt) {
            const bool notlast = (kt + 1 < nkt);
            if (notlast) { stageK(kt + 1, cur ^ 1); loadV(kt + 1); }

            if (kt * 128 <= q_wave_max) {
                const unsigned char* Kcur = lds + cur * 16384;
                const unsigned char* Vcur = lds + 32768 + cur * 16384;

                f32x16 st[4];
#pragma unroll
                for (int kh = 0; kh < 4; ++kh) {
                    f32x16 acc = {};
#pragma unroll
                    for (int dc = 0; dc < 4; ++dc) {
                        const unsigned off = (kbase + (unsigned)(kh * 4096 + dc * 32)) ^ ksw;
                        const bf16x8 ka = *reinterpret_cast<const bf16x8*>(Kcur + off);
                        acc = __builtin_amdgcn_mfma_f32_32x32x16_bf16(ka, qf[dc], acc, 0, 0, 0);
                    }
                    st[kh] = acc;
                }

                if (kt >= 2 * qt) {
#pragma unroll
                    for (int kh = 0; kh < 4; ++kh)
#pragma unroll
                        for (int r = 0; r < 16; ++r) {
                            const int kg = kt * 128 + kh * 32 + (r & 3) + 8 * (r >> 2) + 4 * hi;
                            if (kg > q_glob) st[kh][r] = -3.0e38f;
                        }
                }

                float tm = -3.0e38f;
#pragma unroll
                for (int kh = 0; kh < 4; ++kh)
#pragma unroll
                    for (int r = 0; r < 16; ++r) tm = fmaxf(tm, st[kh][r]);
                tm = fmaxf(tm, __shfl_xor(tm, 32));

                if (!__all(tm <= mrun + 8.0f)) {
                    const float mnew = fmaxf(mrun, tm);
                    const float rsc = EXP2F(mrun - mnew);
                    mrun = mnew;
                    lsum *= rsc;
#pragma unroll
                    for (int dh = 0; dh < 2; ++dh)
#pragma unroll
                        for (int r = 0; r < 16; ++r) oac[dh][r] *= rsc;
                }

                float ps = 0.f;
#pragma unroll
                for (int kh = 0; kh < 4; ++kh)
#pragma unroll
                    for (int r = 0; r < 16; ++r) {
                        const float p = EXP2F(st[kh][r] - mrun);
                        st[kh][r] = p;
                        ps += p;
                    }
                ps += __shfl_xor(ps, 32);
                lsum += ps;

                bf16x8 pf[8];
#pragma unroll
                for (int kh = 0; kh < 4; ++kh)
#pragma unroll
                    for (int hc = 0; hc < 2; ++hc) {
                        const int b0i = hc * 8;
                        unsigned a  = cvtpk_bf16(st[kh][b0i + 0], st[kh][b0i + 1]);
                        unsigned b  = cvtpk_bf16(st[kh][b0i + 4], st[kh][b0i + 5]);
                        unsigned a2 = cvtpk_bf16(st[kh][b0i + 2], st[kh][b0i + 3]);
                        unsigned b2 = cvtpk_bf16(st[kh][b0i + 6], st[kh][b0i + 7]);
                        plswap(a, b, lo_half);
                        plswap(a2, b2, lo_half);
                        u32x4 words = { a, a2, b, b2 };
                        pf[kh * 2 + hc] = __builtin_bit_cast(bf16x8, words);
                    }

#pragma unroll
                for (int dh = 0; dh < 2; ++dh) {
                    const int d = dh * 32 + ll;
                    const unsigned vsw = ((unsigned)((d ^ (d >> 4)) & 15)) << 4;
                    const unsigned vbb = (unsigned)(d * 256 + hi * 16);
#pragma unroll
                    for (int kc = 0; kc < 8; ++kc) {
                        const unsigned off = (vbb + (unsigned)(kc * 32)) ^ vsw;
                        const bf16x8 vfr = *reinterpret_cast<const bf16x8*>(Vcur + off);
                        oac[dh] = __builtin_amdgcn_mfma_f32_32x32x16_bf16(vfr, pf[kc], oac[dh], 0, 0, 0);
                    }
                }
            }

            if (notlast) writeV(cur ^ 1);
            __syncthreads();
            cur ^= 1;
        }

        const float inv = 1.0f / lsum;
        bf16_t* op = Og + (size_t)(sq * SEQLEN + q_glob) * E_DIM + h * 64;
#pragma unroll
        for (int dh = 0; dh < 2; ++dh)
#pragma unroll
            for (int rq = 0; rq < 4; ++rq) {
                const int d0 = dh * 32 + 8 * rq + 4 * hi;
                bf16x4 ov;
#pragma unroll
                for (int j = 0; j < 4; ++j)
                    ov[j] = (bf16_t)(oac[dh][rq * 4 + j] * inv);
                *reinterpret_cast<bf16x4*>(op + d0) = ov;
            }
    }
}

// ---------------------------------------------------------------------------
extern "C" void kernel_launch(void* const* d_in, const int* in_sizes, int n_in,
                              void* d_out, int out_size, void* d_ws, size_t ws_size,
                              hipStream_t stream) {
    const float* hid = (const float*)d_in[0];
    const float* Wq  = (const float*)d_in[1];
    const float* bq  = (const float*)d_in[2];
    const float* Wk  = (const float*)d_in[3];
    const float* bk  = (const float*)d_in[4];
    const float* Wv  = (const float*)d_in[5];
    const float* bv  = (const float*)d_in[6];
    const float* Wo  = (const float*)d_in[7];
    const float* bo  = (const float*)d_in[8];
    float* out = (float*)d_out;

    const size_t TE = (size_t)T_TOK * E_DIM;
    const size_t EE = (size_t)E_DIM * E_DIM;

    bf16_t* ws   = (bf16_t*)d_ws;
    bf16_t* hidB = ws;                 // later reused as attention output
    bf16_t* qkvB = ws + TE;            // [8192][6144]
    bf16_t* Wcat = qkvB + 3 * TE;      // [6144][2048] = Wq|Wk|Wv rows
    bf16_t* WoB  = Wcat + 3 * EE;

    cvt_all<<<4096, 256, 0, stream>>>(hid, Wq, Wk, Wv, Wo, hidB, Wcat, WoB);

    // Q pre-scaled by D^-0.5 * log2(e): attention runs in exp2 domain.
    const float QSCALE = 0.125f * 1.4426950408889634f;

    gemm32r<true><<<dim3((T_TOK / 256) * (LDQ / 256)), 512, 0, stream>>>(
        hidB, Wcat, bq, bk, bv, qkvB, T_TOK, LDQ, QSCALE, 2048);

    attn_fwd3<<<dim3(512), 512, 0, stream>>>(qkvB, hidB);

    gemm64<false><<<dim3((T_TOK / 256) * (E_DIM / 256)), 512, 0, stream>>>(
        hidB, WoB, bo, bo, bo, out, T_TOK, E_DIM, 1.0f, 0);
}

// Round 15
// 383.474 us; speedup vs baseline: 6.4695x; 6.4695x over previous
//
#include <hip/hip_runtime.h>
#include <hip/hip_bf16.h>

typedef __bf16 bf16_t;
typedef __bf16 bf16x8 __attribute__((ext_vector_type(8)));
typedef __bf16 bf16x4 __attribute__((ext_vector_type(4)));
typedef float f32x4 __attribute__((ext_vector_type(4)));
typedef float f32x16 __attribute__((ext_vector_type(16)));
typedef unsigned short u16x8 __attribute__((ext_vector_type(8)));
typedef unsigned int u32x4 __attribute__((ext_vector_type(4)));

#define T_TOK 8192
#define E_DIM 2048
#define NHEAD 32
#define SEQLEN 1024
#define NSEQ 8
#define LDQ 6144

#if __has_builtin(__builtin_amdgcn_exp2f)
#define EXP2F(x) __builtin_amdgcn_exp2f(x)
#else
#define EXP2F(x) exp2f(x)
#endif

static __device__ inline unsigned cvtpk_bf16(float lo, float hi) {
    unsigned r;
    asm("v_cvt_pk_bf16_f32 %0, %1, %2" : "=v"(r) : "v"(lo), "v"(hi));
    return r;
}

static __device__ inline void plswap(unsigned &x, unsigned &y, bool lo_half) {
#if __has_builtin(__builtin_amdgcn_permlane32_swap)
    auto r = __builtin_amdgcn_permlane32_swap(x, y, false, false);
    x = r[0]; y = r[1];
#else
    unsigned xs = __shfl_xor(x, 32), ys = __shfl_xor(y, 32);
    unsigned nx = lo_half ? x : ys;
    unsigned ny = lo_half ? xs : y;
    x = nx; y = ny;
#endif
}

// ---------------- fused fp32 -> bf16 conversion (5 regions, 1 launch) ------
__global__ void cvt_all(const float* __restrict__ hid, const float* __restrict__ Wq,
                        const float* __restrict__ Wk, const float* __restrict__ Wv,
                        const float* __restrict__ Wo, bf16_t* __restrict__ hidB,
                        bf16_t* __restrict__ Wcat, bf16_t* __restrict__ WoB) {
    const int TE4 = (T_TOK * E_DIM) / 4;
    const int EE4 = (E_DIM * E_DIM) / 4;
    const float* src;
    bf16_t* dst;
    int n4, base, nb;
    const int bid = blockIdx.x;
    if (bid < 2048)      { src = hid; dst = hidB;              n4 = TE4; base = 0;    nb = 2048; }
    else if (bid < 2560) { src = Wq;  dst = Wcat;              n4 = EE4; base = 2048; nb = 512; }
    else if (bid < 3072) { src = Wk;  dst = Wcat + 4 * EE4;    n4 = EE4; base = 2560; nb = 512; }
    else if (bid < 3584) { src = Wv;  dst = Wcat + 8 * EE4;    n4 = EE4; base = 3072; nb = 512; }
    else                 { src = Wo;  dst = WoB;               n4 = EE4; base = 3584; nb = 512; }
    const int stride = nb * 256;
    for (int i = (bid - base) * 256 + threadIdx.x; i < n4; i += stride) {
        const float4 v = reinterpret_cast<const float4*>(src)[i];
        bf16x4 o;
        o[0] = (bf16_t)v.x; o[1] = (bf16_t)v.y; o[2] = (bf16_t)v.z; o[3] = (bf16_t)v.w;
        reinterpret_cast<bf16x4*>(dst)[i] = o;
    }
}

// ---------------- GEMM 256x256, BK=32, ring-2, 64KB LDS, 2 blocks/CU -------
// R14 retry with the launch_bounds bug fixed: (512,4) forced VGPR=64 and
// spilled the accumulator (FETCH 3.4GB of scratch, 2414us). (512,2) lets the
// allocator use ~112 VGPR (R8 measured) — then 2 blocks/CU fit by ACTUAL
// resources (LDS 2x64KB=128<=160KB, 4 waves/SIMD x 112<=128 VGPR budget).
// Cross-block TLP: one block's MFMA burst covers the other's barrier stalls.
template<bool OUT_BF16>
__global__ __launch_bounds__(512, 2)
void gemm32r(const bf16_t* __restrict__ A, const bf16_t* __restrict__ B,
             const float* __restrict__ b0, const float* __restrict__ b1,
             const float* __restrict__ b2, void* __restrict__ Cout,
             int M, int N, float qs, int qlim) {
    constexpr int K = 2048;
    constexpr int NK = K / 32;   // 64
    __shared__ alignas(16) unsigned char lds[65536];
    const int tid = threadIdx.x;
    const int wid = tid >> 6, l = tid & 63;
    const int cpx = gridDim.x >> 3;
    const int id = (blockIdx.x & 7) * cpx + (blockIdx.x >> 3);
    const int sb = id >> 5, si = id & 31;
    const int smw = (M >> 8) >> 3;
    const int bm = (sb % smw) * 8 + (si & 7);
    const int bn = (sb / smw) * 4 + (si >> 3);
    const int wrow = (wid >> 2) * 128, wcol = (wid & 3) * 64;
    const int lr = l & 15, lg = l >> 4;

    f32x4 acc[8][4] = {};

    const bf16_t* aBase = A + (size_t)(bm * 256) * K;
    const bf16_t* bBase = B + (size_t)(bn * 256) * K;
    const int sr = l >> 2;           // 0..15: row within 16-row chunk
    const int sc = (l & 3) * 16;     // byte col within 64B row

    auto stage = [&](int t, int buf) {
        unsigned char* base = lds + buf * 32768;
#pragma unroll
        for (int c = 0; c < 2; ++c) {
            const int chunk = wid * 2 + c;
            const int r = chunk * 16 + sr;
            const int cb = sc ^ (((r >> 1) & 3) << 4);
            __builtin_amdgcn_global_load_lds(
                (const __attribute__((address_space(1))) void*)(aBase + (size_t)r * K + t * 32 + (cb >> 1)),
                (__attribute__((address_space(3))) void*)(base + chunk * 1024), 16, 0, 0);
            __builtin_amdgcn_global_load_lds(
                (const __attribute__((address_space(1))) void*)(bBase + (size_t)r * K + t * 32 + (cb >> 1)),
                (__attribute__((address_space(3))) void*)(base + 16384 + chunk * 1024), 16, 0, 0);
        }
    };

    stage(0, 0);
    asm volatile("s_waitcnt vmcnt(0)" ::: "memory");
    __builtin_amdgcn_s_barrier();

#pragma unroll 1
    for (int t = 0; t < NK; ++t) {
        if (t + 1 < NK) stage(t + 1, (t + 1) & 1);   // buf read during t-1, free
        const unsigned char* Ab = lds + (t & 1) * 32768;
        const unsigned char* Bb = Ab + 16384;
        bf16x8 bfv[4], af[8];
#pragma unroll
        for (int n = 0; n < 4; ++n) {
            const int r = wcol + n * 16 + lr;
            bfv[n] = *reinterpret_cast<const bf16x8*>(Bb + r * 64 + ((lg * 16) ^ (((r >> 1) & 3) << 4)));
        }
#pragma unroll
        for (int m = 0; m < 8; ++m) {
            const int r = wrow + m * 16 + lr;
            af[m] = *reinterpret_cast<const bf16x8*>(Ab + r * 64 + ((lg * 16) ^ (((r >> 1) & 3) << 4)));
        }
        __builtin_amdgcn_s_setprio(1);
#pragma unroll
        for (int m = 0; m < 8; ++m)
#pragma unroll
            for (int n = 0; n < 4; ++n)
                acc[m][n] = __builtin_amdgcn_mfma_f32_16x16x32_bf16(af[m], bfv[n], acc[m][n], 0, 0, 0);
        __builtin_amdgcn_s_setprio(0);
        if (t == NK - 1) break;
        asm volatile("s_waitcnt vmcnt(0)" ::: "memory");  // stage(t+1) issued ~1 tile ago
        __builtin_amdgcn_s_barrier();
    }

    // epilogue: C[row=(l>>4)*4+j][col=l&15] per fragment
    const int r0 = bm * 256 + wrow + lg * 4;
    const int c0 = bn * 256 + wcol + lr;
#pragma unroll
    for (int n = 0; n < 4; ++n) {
        const int cc = c0 + n * 16;
        const float bias = (cc < 2048) ? b0[cc] : (cc < 4096 ? b1[cc - 2048] : b2[cc - 4096]);
        const float sc2 = (cc < qlim) ? qs : 1.0f;
#pragma unroll
        for (int m = 0; m < 8; ++m)
#pragma unroll
            for (int j = 0; j < 4; ++j) {
                const int rr = r0 + m * 16 + j;
                const float v = (acc[m][n][j] + bias) * sc2;
                if (OUT_BF16) ((bf16_t*)Cout)[(size_t)rr * N + cc] = (bf16_t)v;
                else          ((float*)Cout)[(size_t)rr * N + cc] = v;
            }
    }
}

// ---------------- GEMM 256x256, BK=64, ring-2 (R10 best — used for Wo) -----
template<bool OUT_BF16>
__global__ __launch_bounds__(512, 2)
void gemm64(const bf16_t* __restrict__ A, const bf16_t* __restrict__ B,
            const float* __restrict__ b0, const float* __restrict__ b1,
            const float* __restrict__ b2, void* __restrict__ Cout,
            int M, int N, float qs, int qlim) {
    constexpr int K = 2048;
    constexpr int NK = K / 64;   // 32
    __shared__ alignas(16) unsigned char lds[131072];
    const int tid = threadIdx.x;
    const int wid = tid >> 6, l = tid & 63;
    const int cpx = gridDim.x >> 3;
    const int id = (blockIdx.x & 7) * cpx + (blockIdx.x >> 3);
    const int sb = id >> 5, si = id & 31;
    const int smw = (M >> 8) >> 3;
    const int bm = (sb % smw) * 8 + (si & 7);
    const int bn = (sb / smw) * 4 + (si >> 3);
    const int wrow = (wid >> 2) * 128, wcol = (wid & 3) * 64;
    const int lr = l & 15, lg = l >> 4;

    f32x4 acc[8][4] = {};

    const bf16_t* aBase = A + (size_t)(bm * 256) * K;
    const bf16_t* bBase = B + (size_t)(bn * 256) * K;

    const int srw = l >> 3;
    const int scb0 = (l & 7) * 16;
    auto stage = [&](int t, int buf) {
        unsigned char* base = lds + buf * 65536;
#pragma unroll
        for (int i = 0; i < 4; ++i) {
            const int chunk = wid * 4 + i;
            const int r = chunk * 8 + srw;
            const int cb = scb0 ^ ((r & 7) << 4);
            __builtin_amdgcn_global_load_lds(
                (const __attribute__((address_space(1))) void*)(aBase + (size_t)r * K + t * 64 + (cb >> 1)),
                (__attribute__((address_space(3))) void*)(base + chunk * 1024), 16, 0, 0);
        }
#pragma unroll
        for (int i = 0; i < 4; ++i) {
            const int chunk = wid * 4 + i;
            const int r = chunk * 8 + srw;
            const int cb = scb0 ^ ((r & 7) << 4);
            __builtin_amdgcn_global_load_lds(
                (const __attribute__((address_space(1))) void*)(bBase + (size_t)r * K + t * 64 + (cb >> 1)),
                (__attribute__((address_space(3))) void*)(base + 32768 + chunk * 1024), 16, 0, 0);
        }
    };

    stage(0, 0);
    asm volatile("s_waitcnt vmcnt(0)" ::: "memory");
    __builtin_amdgcn_s_barrier();

#pragma unroll 1
    for (int t = 0; t < NK; ++t) {
        if (t + 1 < NK) stage(t + 1, (t + 1) & 1);
        const unsigned char* Ab = lds + (t & 1) * 65536;
        const unsigned char* Bb = Ab + 32768;
        bf16x8 af[8][2], bfv[4][2];
#pragma unroll
        for (int n = 0; n < 4; ++n) {
            const int r = wcol + n * 16 + lr;
#pragma unroll
            for (int ks = 0; ks < 2; ++ks)
                bfv[n][ks] = *reinterpret_cast<const bf16x8*>(
                    Bb + r * 128 + (((unsigned)(ks * 64 + lg * 16)) ^ ((r & 7) << 4)));
        }
#pragma unroll
        for (int m = 0; m < 8; ++m) {
            const int r = wrow + m * 16 + lr;
#pragma unroll
            for (int ks = 0; ks < 2; ++ks)
                af[m][ks] = *reinterpret_cast<const bf16x8*>(
                    Ab + r * 128 + (((unsigned)(ks * 64 + lg * 16)) ^ ((r & 7) << 4)));
        }
        __builtin_amdgcn_s_setprio(1);
#pragma unroll
        for (int m = 0; m < 8; ++m)
#pragma unroll
            for (int n = 0; n < 4; ++n)
#pragma unroll
                for (int ks = 0; ks < 2; ++ks)
                    acc[m][n] = __builtin_amdgcn_mfma_f32_16x16x32_bf16(af[m][ks], bfv[n][ks], acc[m][n], 0, 0, 0);
        __builtin_amdgcn_s_setprio(0);
        if (t == NK - 1) break;
        asm volatile("s_waitcnt vmcnt(0)" ::: "memory");
        __builtin_amdgcn_s_barrier();
    }

    const int r0 = bm * 256 + wrow + lg * 4;
    const int c0 = bn * 256 + wcol + lr;
#pragma unroll
    for (int n = 0; n < 4; ++n) {
        const int cc = c0 + n * 16;
        const float bias = (cc < 2048) ? b0[cc] : (cc < 4096 ? b1[cc - 2048] : b2[cc - 4096]);
        const float sc2 = (cc < qlim) ? qs : 1.0f;
#pragma unroll
        for (int m = 0; m < 8; ++m)
#pragma unroll
            for (int j = 0; j < 4; ++j) {
                const int rr = r0 + m * 16 + j;
                const float v = (acc[m][n][j] + bias) * sc2;
                if (OUT_BF16) ((bf16_t*)Cout)[(size_t)rr * N + cc] = (bf16_t)v;
                else          ((float*)Cout)[(size_t)rr * N + cc] = v;
            }
    }
}

// ---------------- Flash attention, 8-wave 32x32 swapped-QK^T, paired qt ----
__global__ __launch_bounds__(512, 2)
void attn_fwd3(const bf16_t* __restrict__ QKV, bf16_t* __restrict__ Og) {
    const int orig = blockIdx.x;               // 0..511
    const int id = (orig & 7) * 64 + (orig >> 3);
    const int grp = id >> 1;                   // (h, sq)
    const int pairIdx = id & 1;
    const int h = grp & 31;
    const int sq = grp >> 5;

    const int tid = threadIdx.x;
    const int w = tid >> 6;
    const int l = tid & 63;
    const int ll = l & 31;
    const int hi = l >> 5;
    const bool lo_half = (hi == 0);

    __shared__ alignas(16) unsigned char lds[65536];  // K[2][16KB] + V[2][16KB]

    const bf16_t* Qg = QKV;
    const bf16_t* Kg = QKV + 2048;
    const bf16_t* Vg = QKV + 4096;
    const size_t kvbase = (size_t)(sq * SEQLEN) * LDQ + h * 64;

    bf16x8 vr0, vr1;
    const int vk0 = l * 2;
    const int vd0 = w * 8;

    auto stageK = [&](int kt, int buf) {
#pragma unroll
        for (int c = 0; c < 2; ++c) {
            const int o = (w * 2 + c) * 1024 + l * 16;
            const int r = o >> 7;
            const int swb = (o & 127) ^ ((r & 7) << 4);
            const bf16_t* src = Kg + kvbase + (size_t)(kt * 128 + r) * LDQ + (swb >> 1);
            __builtin_amdgcn_global_load_lds(
                (const __attribute__((address_space(1))) void*)src,
                (__attribute__((address_space(3))) void*)(lds + buf * 16384 + (w * 2 + c) * 1024),
                16, 0, 0);
        }
    };
    auto loadV = [&](int kt) {
        const bf16_t* vp = Vg + kvbase + (size_t)(kt * 128 + vk0) * LDQ + vd0;
        vr0 = *reinterpret_cast<const bf16x8*>(vp);
        vr1 = *reinterpret_cast<const bf16x8*>(vp + LDQ);
    };
    auto writeV = [&](int buf) {
        u16x8 s0 = __builtin_bit_cast(u16x8, vr0);
        u16x8 s1 = __builtin_bit_cast(u16x8, vr1);
        unsigned char* vb = lds + 32768 + buf * 16384;
#pragma unroll
        for (int e = 0; e < 8; ++e) {
            const int d = vd0 + e;
            unsigned off = (unsigned)(d * 256 + vk0 * 2);
            off ^= ((unsigned)((d ^ (d >> 4)) & 15)) << 4;
            *reinterpret_cast<unsigned*>(vb + off) = (unsigned)s0[e] | ((unsigned)s1[e] << 16);
        }
    };

    const unsigned ksw = (unsigned)((l & 7) << 4);
    const unsigned kbase = (unsigned)(ll * 128 + hi * 16);

#pragma unroll 1
    for (int seg = 0; seg < 2; ++seg) {
        const int qt = pairIdx ? (seg ? 2 : 1) : (seg ? 3 : 0);

        const int q_glob = qt * 256 + w * 32 + ll;
        const bf16_t* qp = Qg + (size_t)(sq * SEQLEN + q_glob) * LDQ + h * 64 + hi * 8;
        bf16x8 qf[4];
#pragma unroll
        for (int dc = 0; dc < 4; ++dc)
            qf[dc] = *reinterpret_cast<const bf16x8*>(qp + dc * 16);

        const int nkt = 2 * qt + 2;
        const int q_wave_max = qt * 256 + w * 32 + 31;

        f32x16 oac[2] = {};
        float mrun = -3.0e38f, lsum = 0.f;

        stageK(0, 0);
        loadV(0);
        writeV(0);
        __syncthreads();

        int cur = 0;
        for (int kt = 0; kt < nkt; ++kt) {
            const bool notlast = (kt + 1 < nkt);
            if (notlast) { stageK(kt + 1, cur ^ 1); loadV(kt + 1); }

            if (kt * 128 <= q_wave_max) {
                const unsigned char* Kcur = lds + cur * 16384;
                const unsigned char* Vcur = lds + 32768 + cur * 16384;

                f32x16 st[4];
#pragma unroll
                for (int kh = 0; kh < 4; ++kh) {
                    f32x16 acc = {};
#pragma unroll
                    for (int dc = 0; dc < 4; ++dc) {
                        const unsigned off = (kbase + (unsigned)(kh * 4096 + dc * 32)) ^ ksw;
                        const bf16x8 ka = *reinterpret_cast<const bf16x8*>(Kcur + off);
                        acc = __builtin_amdgcn_mfma_f32_32x32x16_bf16(ka, qf[dc], acc, 0, 0, 0);
                    }
                    st[kh] = acc;
                }

                if (kt >= 2 * qt) {
#pragma unroll
                    for (int kh = 0; kh < 4; ++kh)
#pragma unroll
                        for (int r = 0; r < 16; ++r) {
                            const int kg = kt * 128 + kh * 32 + (r & 3) + 8 * (r >> 2) + 4 * hi;
                            if (kg > q_glob) st[kh][r] = -3.0e38f;
                        }
                }

                float tm = -3.0e38f;
#pragma unroll
                for (int kh = 0; kh < 4; ++kh)
#pragma unroll
                    for (int r = 0; r < 16; ++r) tm = fmaxf(tm, st[kh][r]);
                tm = fmaxf(tm, __shfl_xor(tm, 32));

                if (!__all(tm <= mrun + 8.0f)) {
                    const float mnew = fmaxf(mrun, tm);
                    const float rsc = EXP2F(mrun - mnew);
                    mrun = mnew;
                    lsum *= rsc;
#pragma unroll
                    for (int dh = 0; dh < 2; ++dh)
#pragma unroll
                        for (int r = 0; r < 16; ++r) oac[dh][r] *= rsc;
                }

                float ps = 0.f;
#pragma unroll
                for (int kh = 0; kh < 4; ++kh)
#pragma unroll
                    for (int r = 0; r < 16; ++r) {
                        const float p = EXP2F(st[kh][r] - mrun);
                        st[kh][r] = p;
                        ps += p;
                    }
                ps += __shfl_xor(ps, 32);
                lsum += ps;

                bf16x8 pf[8];
#pragma unroll
                for (int kh = 0; kh < 4; ++kh)
#pragma unroll
                    for (int hc = 0; hc < 2; ++hc) {
                        const int b0i = hc * 8;
                        unsigned a  = cvtpk_bf16(st[kh][b0i + 0], st[kh][b0i + 1]);
                        unsigned b  = cvtpk_bf16(st[kh][b0i + 4], st[kh][b0i + 5]);
                        unsigned a2 = cvtpk_bf16(st[kh][b0i + 2], st[kh][b0i + 3]);
                        unsigned b2 = cvtpk_bf16(st[kh][b0i + 6], st[kh][b0i + 7]);
                        plswap(a, b, lo_half);
                        plswap(a2, b2, lo_half);
                        u32x4 words = { a, a2, b, b2 };
                        pf[kh * 2 + hc] = __builtin_bit_cast(bf16x8, words);
                    }

#pragma unroll
                for (int dh = 0; dh < 2; ++dh) {
                    const int d = dh * 32 + ll;
                    const unsigned vsw = ((unsigned)((d ^ (d >> 4)) & 15)) << 4;
                    const unsigned vbb = (unsigned)(d * 256 + hi * 16);
#pragma unroll
                    for (int kc = 0; kc < 8; ++kc) {
                        const unsigned off = (vbb + (unsigned)(kc * 32)) ^ vsw;
                        const bf16x8 vfr = *reinterpret_cast<const bf16x8*>(Vcur + off);
                        oac[dh] = __builtin_amdgcn_mfma_f32_32x32x16_bf16(vfr, pf[kc], oac[dh], 0, 0, 0);
                    }
                }
            }

            if (notlast) writeV(cur ^ 1);
            __syncthreads();
            cur ^= 1;
        }

        const float inv = 1.0f / lsum;
        bf16_t* op = Og + (size_t)(sq * SEQLEN + q_glob) * E_DIM + h * 64;
#pragma unroll
        for (int dh = 0; dh < 2; ++dh)
#pragma unroll
            for (int rq = 0; rq < 4; ++rq) {
                const int d0 = dh * 32 + 8 * rq + 4 * hi;
                bf16x4 ov;
#pragma unroll
                for (int j = 0; j < 4; ++j)
                    ov[j] = (bf16_t)(oac[dh][rq * 4 + j] * inv);
                *reinterpret_cast<bf16x4*>(op + d0) = ov;
            }
    }
}

// ---------------------------------------------------------------------------
extern "C" void kernel_launch(void* const* d_in, const int* in_sizes, int n_in,
                              void* d_out, int out_size, void* d_ws, size_t ws_size,
                              hipStream_t stream) {
    const float* hid = (const float*)d_in[0];
    const float* Wq  = (const float*)d_in[1];
    const float* bq  = (const float*)d_in[2];
    const float* Wk  = (const float*)d_in[3];
    const float* bk  = (const float*)d_in[4];
    const float* Wv  = (const float*)d_in[5];
    const float* bv  = (const float*)d_in[6];
    const float* Wo  = (const float*)d_in[7];
    const float* bo  = (const float*)d_in[8];
    float* out = (float*)d_out;

    const size_t TE = (size_t)T_TOK * E_DIM;
    const size_t EE = (size_t)E_DIM * E_DIM;

    bf16_t* ws   = (bf16_t*)d_ws;
    bf16_t* hidB = ws;                 // later reused as attention output
    bf16_t* qkvB = ws + TE;            // [8192][6144]
    bf16_t* Wcat = qkvB + 3 * TE;      // [6144][2048] = Wq|Wk|Wv rows
    bf16_t* WoB  = Wcat + 3 * EE;

    cvt_all<<<4096, 256, 0, stream>>>(hid, Wq, Wk, Wv, Wo, hidB, Wcat, WoB);

    // Q pre-scaled by D^-0.5 * log2(e): attention runs in exp2 domain.
    const float QSCALE = 0.125f * 1.4426950408889634f;

    gemm32r<true><<<dim3((T_TOK / 256) * (LDQ / 256)), 512, 0, stream>>>(
        hidB, Wcat, bq, bk, bv, qkvB, T_TOK, LDQ, QSCALE, 2048);

    attn_fwd3<<<dim3(512), 512, 0, stream>>>(qkvB, hidB);

    gemm64<false><<<dim3((T_TOK / 256) * (E_DIM / 256)), 512, 0, stream>>>(
        hidB, WoB, bo, bo, bo, out, T_TOK, E_DIM, 1.0f, 0);
}

// Round 16
// 366.896 us; speedup vs baseline: 6.7618x; 1.0452x over previous
//
#include <hip/hip_runtime.h>
#include <hip/hip_bf16.h>

typedef __bf16 bf16_t;
typedef __bf16 bf16x8 __attribute__((ext_vector_type(8)));
typedef __bf16 bf16x4 __attribute__((ext_vector_type(4)));
typedef float f32x4 __attribute__((ext_vector_type(4)));
typedef float f32x16 __attribute__((ext_vector_type(16)));
typedef unsigned short u16x8 __attribute__((ext_vector_type(8)));
typedef unsigned int u32x4 __attribute__((ext_vector_type(4)));

#define T_TOK 8192
#define E_DIM 2048
#define NHEAD 32
#define SEQLEN 1024
#define NSEQ 8
#define LDQ 6144

#if __has_builtin(__builtin_amdgcn_exp2f)
#define EXP2F(x) __builtin_amdgcn_exp2f(x)
#else
#define EXP2F(x) exp2f(x)
#endif

static __device__ inline unsigned cvtpk_bf16(float lo, float hi) {
    unsigned r;
    asm("v_cvt_pk_bf16_f32 %0, %1, %2" : "=v"(r) : "v"(lo), "v"(hi));
    return r;
}

static __device__ inline void plswap(unsigned &x, unsigned &y, bool lo_half) {
#if __has_builtin(__builtin_amdgcn_permlane32_swap)
    auto r = __builtin_amdgcn_permlane32_swap(x, y, false, false);
    x = r[0]; y = r[1];
#else
    unsigned xs = __shfl_xor(x, 32), ys = __shfl_xor(y, 32);
    unsigned nx = lo_half ? x : ys;
    unsigned ny = lo_half ? xs : y;
    x = nx; y = ny;
#endif
}

// ---------------- fused fp32 -> bf16 conversion (5 regions, 1 launch) ------
__global__ void cvt_all(const float* __restrict__ hid, const float* __restrict__ Wq,
                        const float* __restrict__ Wk, const float* __restrict__ Wv,
                        const float* __restrict__ Wo, bf16_t* __restrict__ hidB,
                        bf16_t* __restrict__ Wcat, bf16_t* __restrict__ WoB) {
    const int TE4 = (T_TOK * E_DIM) / 4;
    const int EE4 = (E_DIM * E_DIM) / 4;
    const float* src;
    bf16_t* dst;
    int n4, base, nb;
    const int bid = blockIdx.x;
    if (bid < 2048)      { src = hid; dst = hidB;              n4 = TE4; base = 0;    nb = 2048; }
    else if (bid < 2560) { src = Wq;  dst = Wcat;              n4 = EE4; base = 2048; nb = 512; }
    else if (bid < 3072) { src = Wk;  dst = Wcat + 4 * EE4;    n4 = EE4; base = 2560; nb = 512; }
    else if (bid < 3584) { src = Wv;  dst = Wcat + 8 * EE4;    n4 = EE4; base = 3072; nb = 512; }
    else                 { src = Wo;  dst = WoB;               n4 = EE4; base = 3584; nb = 512; }
    const int stride = nb * 256;
    for (int i = (bid - base) * 256 + threadIdx.x; i < n4; i += stride) {
        const float4 v = reinterpret_cast<const float4*>(src)[i];
        bf16x4 o;
        o[0] = (bf16_t)v.x; o[1] = (bf16_t)v.y; o[2] = (bf16_t)v.z; o[3] = (bf16_t)v.w;
        reinterpret_cast<bf16x4*>(dst)[i] = o;
    }
}

// ---------------- GEMM 256x256, BK=64, ring-2, early-stage (best: R10) -----
// C[M,N] = (A[M,K] * B[N,K]^T + bias) * (col<qlim ? qs : 1), K=2048 fixed.
// 8 waves (2M x 4N), per-wave 128x64. LDS 128KB: 2 bufs x (A 32K + B 32K).
// 32 K-tiles: stage(t+1) issued at TOP of tile t -> ~2500 cyc before the
// tile-end vmcnt(0); 128B LDS rows, swizzle cb ^= (row&7)<<4 (0 conflicts).
// Supertile map: 8bm x 4bn blocks per 32-id group inside each XCD chunk.
// Session notes: 16x16x32 MFMA (32x32x16 bank-conflicts here, R12);
// occupancy >1 block/CU unattainable for this structure (R15); 8-phase /
// counted-vmcnt / lgkm-drain variants all plateau 37-43% MfmaUtil (R3-R7).
template<bool OUT_BF16>
__global__ __launch_bounds__(512, 2)
void gemm64(const bf16_t* __restrict__ A, const bf16_t* __restrict__ B,
            const float* __restrict__ b0, const float* __restrict__ b1,
            const float* __restrict__ b2, void* __restrict__ Cout,
            int M, int N, float qs, int qlim) {
    constexpr int K = 2048;
    constexpr int NK = K / 64;   // 32
    __shared__ alignas(16) unsigned char lds[131072];
    const int tid = threadIdx.x;
    const int wid = tid >> 6, l = tid & 63;
    const int cpx = gridDim.x >> 3;
    const int id = (blockIdx.x & 7) * cpx + (blockIdx.x >> 3);
    const int sb = id >> 5, si = id & 31;
    const int smw = (M >> 8) >> 3;
    const int bm = (sb % smw) * 8 + (si & 7);
    const int bn = (sb / smw) * 4 + (si >> 3);
    const int wrow = (wid >> 2) * 128, wcol = (wid & 3) * 64;
    const int lr = l & 15, lg = l >> 4;

    f32x4 acc[8][4] = {};

    const bf16_t* aBase = A + (size_t)(bm * 256) * K;
    const bf16_t* bBase = B + (size_t)(bn * 256) * K;

    const int srw = l >> 3;            // 0..7 row within chunk
    const int scb0 = (l & 7) * 16;     // byte col within 128B row
    auto stage = [&](int t, int buf) {
        unsigned char* base = lds + buf * 65536;
#pragma unroll
        for (int i = 0; i < 4; ++i) {
            const int chunk = wid * 4 + i;
            const int r = chunk * 8 + srw;
            const int cb = scb0 ^ ((r & 7) << 4);
            __builtin_amdgcn_global_load_lds(
                (const __attribute__((address_space(1))) void*)(aBase + (size_t)r * K + t * 64 + (cb >> 1)),
                (__attribute__((address_space(3))) void*)(base + chunk * 1024), 16, 0, 0);
        }
#pragma unroll
        for (int i = 0; i < 4; ++i) {
            const int chunk = wid * 4 + i;
            const int r = chunk * 8 + srw;
            const int cb = scb0 ^ ((r & 7) << 4);
            __builtin_amdgcn_global_load_lds(
                (const __attribute__((address_space(1))) void*)(bBase + (size_t)r * K + t * 64 + (cb >> 1)),
                (__attribute__((address_space(3))) void*)(base + 32768 + chunk * 1024), 16, 0, 0);
        }
    };

    stage(0, 0);
    asm volatile("s_waitcnt vmcnt(0)" ::: "memory");
    __builtin_amdgcn_s_barrier();

#pragma unroll 1
    for (int t = 0; t < NK; ++t) {
        if (t + 1 < NK) stage(t + 1, (t + 1) & 1);   // early: lands during MFMA
        const unsigned char* Ab = lds + (t & 1) * 65536;
        const unsigned char* Bb = Ab + 32768;
        bf16x8 af[8][2], bfv[4][2];
#pragma unroll
        for (int n = 0; n < 4; ++n) {
            const int r = wcol + n * 16 + lr;
#pragma unroll
            for (int ks = 0; ks < 2; ++ks)
                bfv[n][ks] = *reinterpret_cast<const bf16x8*>(
                    Bb + r * 128 + (((unsigned)(ks * 64 + lg * 16)) ^ ((r & 7) << 4)));
        }
#pragma unroll
        for (int m = 0; m < 8; ++m) {
            const int r = wrow + m * 16 + lr;
#pragma unroll
            for (int ks = 0; ks < 2; ++ks)
                af[m][ks] = *reinterpret_cast<const bf16x8*>(
                    Ab + r * 128 + (((unsigned)(ks * 64 + lg * 16)) ^ ((r & 7) << 4)));
        }
        __builtin_amdgcn_s_setprio(1);
#pragma unroll
        for (int m = 0; m < 8; ++m)
#pragma unroll
            for (int n = 0; n < 4; ++n)
#pragma unroll
                for (int ks = 0; ks < 2; ++ks)
                    acc[m][n] = __builtin_amdgcn_mfma_f32_16x16x32_bf16(af[m][ks], bfv[n][ks], acc[m][n], 0, 0, 0);
        __builtin_amdgcn_s_setprio(0);
        if (t == NK - 1) break;
        asm volatile("s_waitcnt vmcnt(0)" ::: "memory");  // stage(t+1): issued ~2500 cyc ago
        __builtin_amdgcn_s_barrier();
    }

    // epilogue: C[row=(l>>4)*4+j][col=l&15] per fragment
    const int r0 = bm * 256 + wrow + lg * 4;
    const int c0 = bn * 256 + wcol + lr;
#pragma unroll
    for (int n = 0; n < 4; ++n) {
        const int cc = c0 + n * 16;
        const float bias = (cc < 2048) ? b0[cc] : (cc < 4096 ? b1[cc - 2048] : b2[cc - 4096]);
        const float sc2 = (cc < qlim) ? qs : 1.0f;
#pragma unroll
        for (int m = 0; m < 8; ++m)
#pragma unroll
            for (int j = 0; j < 4; ++j) {
                const int rr = r0 + m * 16 + j;
                const float v = (acc[m][n][j] + bias) * sc2;
                if (OUT_BF16) ((bf16_t*)Cout)[(size_t)rr * N + cc] = (bf16_t)v;
                else          ((float*)Cout)[(size_t)rr * N + cc] = v;
            }
    }
}

// ---------------- Flash attention, 8-wave 32x32 swapped-QK^T, paired qt ----
__global__ __launch_bounds__(512, 2)
void attn_fwd3(const bf16_t* __restrict__ QKV, bf16_t* __restrict__ Og) {
    const int orig = blockIdx.x;               // 0..511
    const int id = (orig & 7) * 64 + (orig >> 3);
    const int grp = id >> 1;                   // (h, sq)
    const int pairIdx = id & 1;
    const int h = grp & 31;
    const int sq = grp >> 5;

    const int tid = threadIdx.x;
    const int w = tid >> 6;
    const int l = tid & 63;
    const int ll = l & 31;
    const int hi = l >> 5;
    const bool lo_half = (hi == 0);

    __shared__ alignas(16) unsigned char lds[65536];  // K[2][16KB] + V[2][16KB]

    const bf16_t* Qg = QKV;
    const bf16_t* Kg = QKV + 2048;
    const bf16_t* Vg = QKV + 4096;
    const size_t kvbase = (size_t)(sq * SEQLEN) * LDQ + h * 64;

    bf16x8 vr0, vr1;
    const int vk0 = l * 2;
    const int vd0 = w * 8;

    auto stageK = [&](int kt, int buf) {
#pragma unroll
        for (int c = 0; c < 2; ++c) {
            const int o = (w * 2 + c) * 1024 + l * 16;
            const int r = o >> 7;
            const int swb = (o & 127) ^ ((r & 7) << 4);
            const bf16_t* src = Kg + kvbase + (size_t)(kt * 128 + r) * LDQ + (swb >> 1);
            __builtin_amdgcn_global_load_lds(
                (const __attribute__((address_space(1))) void*)src,
                (__attribute__((address_space(3))) void*)(lds + buf * 16384 + (w * 2 + c) * 1024),
                16, 0, 0);
        }
    };
    auto loadV = [&](int kt) {
        const bf16_t* vp = Vg + kvbase + (size_t)(kt * 128 + vk0) * LDQ + vd0;
        vr0 = *reinterpret_cast<const bf16x8*>(vp);
        vr1 = *reinterpret_cast<const bf16x8*>(vp + LDQ);
    };
    auto writeV = [&](int buf) {
        u16x8 s0 = __builtin_bit_cast(u16x8, vr0);
        u16x8 s1 = __builtin_bit_cast(u16x8, vr1);
        unsigned char* vb = lds + 32768 + buf * 16384;
#pragma unroll
        for (int e = 0; e < 8; ++e) {
            const int d = vd0 + e;
            unsigned off = (unsigned)(d * 256 + vk0 * 2);
            off ^= ((unsigned)((d ^ (d >> 4)) & 15)) << 4;
            *reinterpret_cast<unsigned*>(vb + off) = (unsigned)s0[e] | ((unsigned)s1[e] << 16);
        }
    };

    const unsigned ksw = (unsigned)((l & 7) << 4);
    const unsigned kbase = (unsigned)(ll * 128 + hi * 16);

#pragma unroll 1
    for (int seg = 0; seg < 2; ++seg) {
        const int qt = pairIdx ? (seg ? 2 : 1) : (seg ? 3 : 0);

        const int q_glob = qt * 256 + w * 32 + ll;
        const bf16_t* qp = Qg + (size_t)(sq * SEQLEN + q_glob) * LDQ + h * 64 + hi * 8;
        bf16x8 qf[4];
#pragma unroll
        for (int dc = 0; dc < 4; ++dc)
            qf[dc] = *reinterpret_cast<const bf16x8*>(qp + dc * 16);

        const int nkt = 2 * qt + 2;
        const int q_wave_max = qt * 256 + w * 32 + 31;

        f32x16 oac[2] = {};
        float mrun = -3.0e38f, lsum = 0.f;

        stageK(0, 0);
        loadV(0);
        writeV(0);
        __syncthreads();

        int cur = 0;
        for (int kt = 0; kt < nkt; ++kt) {
            const bool notlast = (kt + 1 < nkt);
            if (notlast) { stageK(kt + 1, cur ^ 1); loadV(kt + 1); }

            if (kt * 128 <= q_wave_max) {
                const unsigned char* Kcur = lds + cur * 16384;
                const unsigned char* Vcur = lds + 32768 + cur * 16384;

                f32x16 st[4];
#pragma unroll
                for (int kh = 0; kh < 4; ++kh) {
                    f32x16 acc = {};
#pragma unroll
                    for (int dc = 0; dc < 4; ++dc) {
                        const unsigned off = (kbase + (unsigned)(kh * 4096 + dc * 32)) ^ ksw;
                        const bf16x8 ka = *reinterpret_cast<const bf16x8*>(Kcur + off);
                        acc = __builtin_amdgcn_mfma_f32_32x32x16_bf16(ka, qf[dc], acc, 0, 0, 0);
                    }
                    st[kh] = acc;
                }

                if (kt >= 2 * qt) {
#pragma unroll
                    for (int kh = 0; kh < 4; ++kh)
#pragma unroll
                        for (int r = 0; r < 16; ++r) {
                            const int kg = kt * 128 + kh * 32 + (r & 3) + 8 * (r >> 2) + 4 * hi;
                            if (kg > q_glob) st[kh][r] = -3.0e38f;
                        }
                }

                float tm = -3.0e38f;
#pragma unroll
                for (int kh = 0; kh < 4; ++kh)
#pragma unroll
                    for (int r = 0; r < 16; ++r) tm = fmaxf(tm, st[kh][r]);
                tm = fmaxf(tm, __shfl_xor(tm, 32));

                if (!__all(tm <= mrun + 8.0f)) {
                    const float mnew = fmaxf(mrun, tm);
                    const float rsc = EXP2F(mrun - mnew);
                    mrun = mnew;
                    lsum *= rsc;
#pragma unroll
                    for (int dh = 0; dh < 2; ++dh)
#pragma unroll
                        for (int r = 0; r < 16; ++r) oac[dh][r] *= rsc;
                }

                float ps = 0.f;
#pragma unroll
                for (int kh = 0; kh < 4; ++kh)
#pragma unroll
                    for (int r = 0; r < 16; ++r) {
                        const float p = EXP2F(st[kh][r] - mrun);
                        st[kh][r] = p;
                        ps += p;
                    }
                ps += __shfl_xor(ps, 32);
                lsum += ps;

                bf16x8 pf[8];
#pragma unroll
                for (int kh = 0; kh < 4; ++kh)
#pragma unroll
                    for (int hc = 0; hc < 2; ++hc) {
                        const int b0i = hc * 8;
                        unsigned a  = cvtpk_bf16(st[kh][b0i + 0], st[kh][b0i + 1]);
                        unsigned b  = cvtpk_bf16(st[kh][b0i + 4], st[kh][b0i + 5]);
                        unsigned a2 = cvtpk_bf16(st[kh][b0i + 2], st[kh][b0i + 3]);
                        unsigned b2 = cvtpk_bf16(st[kh][b0i + 6], st[kh][b0i + 7]);
                        plswap(a, b, lo_half);
                        plswap(a2, b2, lo_half);
                        u32x4 words = { a, a2, b, b2 };
                        pf[kh * 2 + hc] = __builtin_bit_cast(bf16x8, words);
                    }

#pragma unroll
                for (int dh = 0; dh < 2; ++dh) {
                    const int d = dh * 32 + ll;
                    const unsigned vsw = ((unsigned)((d ^ (d >> 4)) & 15)) << 4;
                    const unsigned vbb = (unsigned)(d * 256 + hi * 16);
#pragma unroll
                    for (int kc = 0; kc < 8; ++kc) {
                        const unsigned off = (vbb + (unsigned)(kc * 32)) ^ vsw;
                        const bf16x8 vfr = *reinterpret_cast<const bf16x8*>(Vcur + off);
                        oac[dh] = __builtin_amdgcn_mfma_f32_32x32x16_bf16(vfr, pf[kc], oac[dh], 0, 0, 0);
                    }
                }
            }

            if (notlast) writeV(cur ^ 1);
            __syncthreads();
            cur ^= 1;
        }

        const float inv = 1.0f / lsum;
        bf16_t* op = Og + (size_t)(sq * SEQLEN + q_glob) * E_DIM + h * 64;
#pragma unroll
        for (int dh = 0; dh < 2; ++dh)
#pragma unroll
            for (int rq = 0; rq < 4; ++rq) {
                const int d0 = dh * 32 + 8 * rq + 4 * hi;
                bf16x4 ov;
#pragma unroll
                for (int j = 0; j < 4; ++j)
                    ov[j] = (bf16_t)(oac[dh][rq * 4 + j] * inv);
                *reinterpret_cast<bf16x4*>(op + d0) = ov;
            }
    }
}

// ---------------------------------------------------------------------------
extern "C" void kernel_launch(void* const* d_in, const int* in_sizes, int n_in,
                              void* d_out, int out_size, void* d_ws, size_t ws_size,
                              hipStream_t stream) {
    const float* hid = (const float*)d_in[0];
    const float* Wq  = (const float*)d_in[1];
    const float* bq  = (const float*)d_in[2];
    const float* Wk  = (const float*)d_in[3];
    const float* bk  = (const float*)d_in[4];
    const float* Wv  = (const float*)d_in[5];
    const float* bv  = (const float*)d_in[6];
    const float* Wo  = (const float*)d_in[7];
    const float* bo  = (const float*)d_in[8];
    float* out = (float*)d_out;

    const size_t TE = (size_t)T_TOK * E_DIM;
    const size_t EE = (size_t)E_DIM * E_DIM;

    bf16_t* ws   = (bf16_t*)d_ws;
    bf16_t* hidB = ws;                 // later reused as attention output
    bf16_t* qkvB = ws + TE;            // [8192][6144]
    bf16_t* Wcat = qkvB + 3 * TE;      // [6144][2048] = Wq|Wk|Wv rows
    bf16_t* WoB  = Wcat + 3 * EE;

    cvt_all<<<4096, 256, 0, stream>>>(hid, Wq, Wk, Wv, Wo, hidB, Wcat, WoB);

    // Q pre-scaled by D^-0.5 * log2(e): attention runs in exp2 domain.
    const float QSCALE = 0.125f * 1.4426950408889634f;

    gemm64<true><<<dim3((T_TOK / 256) * (LDQ / 256)), 512, 0, stream>>>(
        hidB, Wcat, bq, bk, bv, qkvB, T_TOK, LDQ, QSCALE, 2048);

    attn_fwd3<<<dim3(512), 512, 0, stream>>>(qkvB, hidB);

    gemm64<false><<<dim3((T_TOK / 256) * (E_DIM / 256)), 512, 0, stream>>>(
        hidB, WoB, bo, bo, bo, out, T_TOK, E_DIM, 1.0f, 0);
}